// Round 1
// baseline (1232.303 us; speedup 1.0000x reference)
//
#include <hip/hip_runtime.h>

typedef unsigned short u16;
typedef short bf16x8 __attribute__((ext_vector_type(8)));
typedef float f32x4 __attribute__((ext_vector_type(4)));

__device__ __forceinline__ u16 f2bf(float f) {
    unsigned u = __float_as_uint(f);
    u = (u + 0x7fffu + ((u >> 16) & 1u)) >> 16;
    return (u16)u;
}
__device__ __forceinline__ float bf2f(u16 h) {
    return __uint_as_float(((unsigned)h) << 16);
}
__device__ __forceinline__ unsigned pk2(float a, float b) {
    unsigned ua = __float_as_uint(a);
    unsigned ub = __float_as_uint(b);
    ua = (ua + 0x7fffu + ((ua >> 16) & 1u)) >> 16;
    ub = (ub + 0x7fffu + ((ub >> 16) & 1u)) >> 16;
    return ua | (ub << 16);
}
__device__ __forceinline__ void async16(void* lds, const void* g) {
    __builtin_amdgcn_global_load_lds(
        (const __attribute__((address_space(1))) void*)g,
        (__attribute__((address_space(3))) void*)lds, 16, 0, 0);
}

// ---------------------------------------------------------------------------
// prep_weights: WpT bf16 [256][2048] (=Wp^T), WqkvsT bf16 [2048][256]
// (rows: q 0..511 | k 512..1023 | v 1024..1535 | s 1536..2047; cols = D index)
// ---------------------------------------------------------------------------
__global__ __launch_bounds__(256) void prep_weights(
    const float* __restrict__ Wp, const float* __restrict__ Wq,
    const float* __restrict__ Wk, const float* __restrict__ Wv,
    const float* __restrict__ Ws, u16* __restrict__ WpT, u16* __restrict__ WT)
{
    int id = blockIdx.x * 256 + threadIdx.x;   // 0 .. 1048575
    if (id < 524288) {
        int n = id & 255, k = id >> 8;                       // k: 0..2047
        WpT[(size_t)n * 2048 + k] = f2bf(Wp[(size_t)k * 256 + n]);
    } else {
        int id2 = id - 524288;
        int o = id2 & 511;
        int k = (id2 >> 9) & 255;
        int mat = id2 >> 17;                                 // 0..3
        const float* W = (mat == 0) ? Wq : (mat == 1) ? Wk : (mat == 2) ? Wv : Ws;
        WT[(size_t)(mat * 512 + o) * 256 + k] = f2bf(W[(size_t)k * 512 + o]);
    }
}

// ---------------------------------------------------------------------------
// prep_mask: M[dst][src] = ln(multiplicity) or -1e30
// ---------------------------------------------------------------------------
__global__ __launch_bounds__(256) void prep_mask(const int* __restrict__ ei,
                                                 float* __restrict__ M)
{
    __shared__ int cnt[4096];
    int t = threadIdx.x;
    for (int i = t; i < 4096; i += 256) cnt[i] = 0;
    __syncthreads();
    for (int e = t; e < 1024; e += 256) {
        int s = ei[e];
        int d = ei[1024 + e];
        atomicAdd(&cnt[d * 64 + s], 1);
    }
    __syncthreads();
    for (int i = t; i < 4096; i += 256) {
        int c = cnt[i];
        M[i] = (c > 0) ? logf((float)c) : -1e30f;
    }
}

// ---------------------------------------------------------------------------
// gemm1: Xp_bf16[65536][256] = bf16(X[65536][2048]) @ bf16(Wp) + bp
// A: fp32 global -> cvt -> LDS bf16 [128][40] (pad). B: WpT via
// global_load_lds, XOR-swizzled chunks [128][32].
// ---------------------------------------------------------------------------
__global__ __launch_bounds__(256) void gemm1(const float* __restrict__ X,
                                             const u16* __restrict__ WpT,
                                             const float* __restrict__ bp,
                                             u16* __restrict__ Xp)
{
    __shared__ alignas(16) u16 As[128 * 40];
    __shared__ alignas(16) u16 Bs[128 * 32];
    const int t = threadIdx.x;
    const int lane = t & 63, wave = t >> 6;
    const int m0 = blockIdx.x * 128, n0 = blockIdx.y * 128;
    const int wm = (wave >> 1) * 64, wn = (wave & 1) * 64;
    const int lr = lane & 15, q8 = lane >> 4;

    const int ar = t >> 1, ah = (t & 1) * 16;
    const float* aptr = X + (size_t)(m0 + ar) * 2048 + ah;

    const int c0 = wave * 64 + lane;
    const int c1 = 256 + wave * 64 + lane;
    const int br0 = c0 >> 2, bg0 = (c0 & 3) ^ (br0 & 3);
    const int br1 = c1 >> 2, bg1 = (c1 & 3) ^ (br1 & 3);
    const u16* bbase = WpT + (size_t)n0 * 2048;
    u16* blds0 = &Bs[(wave * 64) * 8];
    u16* blds1 = &Bs[(256 + wave * 64) * 8];

    const f32x4 z4 = {0.f, 0.f, 0.f, 0.f};
    f32x4 acc[4][4];
#pragma unroll
    for (int i = 0; i < 4; ++i)
#pragma unroll
        for (int j = 0; j < 4; ++j) acc[i][j] = z4;

    for (int kk = 0; kk < 64; ++kk) {
        const int k0 = kk * 32;
        async16(blds0, bbase + (size_t)br0 * 2048 + k0 + bg0 * 8);
        async16(blds1, bbase + (size_t)br1 * 2048 + k0 + bg1 * 8);
        const float4 x0 = *(const float4*)(aptr + k0);
        const float4 x1 = *(const float4*)(aptr + k0 + 4);
        const float4 x2 = *(const float4*)(aptr + k0 + 8);
        const float4 x3 = *(const float4*)(aptr + k0 + 12);
        uint4 p0, p1;
        p0.x = pk2(x0.x, x0.y); p0.y = pk2(x0.z, x0.w);
        p0.z = pk2(x1.x, x1.y); p0.w = pk2(x1.z, x1.w);
        p1.x = pk2(x2.x, x2.y); p1.y = pk2(x2.z, x2.w);
        p1.z = pk2(x3.x, x3.y); p1.w = pk2(x3.z, x3.w);
        *(uint4*)&As[ar * 40 + ah] = p0;
        *(uint4*)&As[ar * 40 + ah + 8] = p1;
        __syncthreads();
        bf16x8 af[4], bfr[4];
#pragma unroll
        for (int i = 0; i < 4; ++i)
            af[i] = *(const bf16x8*)&As[(wm + i * 16 + lr) * 40 + q8 * 8];
#pragma unroll
        for (int j = 0; j < 4; ++j) {
            int rn = wn + j * 16 + lr;
            bfr[j] = *(const bf16x8*)&Bs[rn * 32 + ((q8 ^ (rn & 3)) * 8)];
        }
#pragma unroll
        for (int i = 0; i < 4; ++i)
#pragma unroll
            for (int j = 0; j < 4; ++j)
                acc[i][j] = __builtin_amdgcn_mfma_f32_16x16x32_bf16(
                    af[i], bfr[j], acc[i][j], 0, 0, 0);
        __syncthreads();
    }
#pragma unroll
    for (int j = 0; j < 4; ++j) {
        const int col = n0 + wn + j * 16 + lr;
        const float bias = bp[col];
#pragma unroll
        for (int i = 0; i < 4; ++i)
#pragma unroll
            for (int r = 0; r < 4; ++r) {
                int row = m0 + wm + i * 16 + q8 * 4 + r;
                Xp[(size_t)row * 256 + col] = f2bf(acc[i][j][r] + bias);
            }
    }
}

// ---------------------------------------------------------------------------
// fused_attn: one block per batch. Xp[b] in LDS (swizzled); per head:
// QKV GEMM (MFMA, B-frags from L2 weights), S = q*k^T/8 + mask (MFMA),
// softmax, PV (MFMA), graph-mean accumulate. Epilogue: skip via xbar, @Wr.
// ---------------------------------------------------------------------------
__global__ __launch_bounds__(256) void fused_attn(
    const u16* __restrict__ Xp, const u16* __restrict__ WT,
    const float* __restrict__ Mmask,
    const float* __restrict__ bq, const float* __restrict__ bk,
    const float* __restrict__ bv, const float* __restrict__ bs,
    const float* __restrict__ Wr, const float* __restrict__ br,
    float* __restrict__ out)
{
    __shared__ alignas(16) u16 Xs[64 * 256];
    __shared__ alignas(16) u16 Qs[64 * 72];
    __shared__ alignas(16) u16 Ks[64 * 72];
    __shared__ alignas(16) u16 Vt[64 * 72];   // transposed: Vt[c][src]
    __shared__ alignas(16) u16 Ps[64 * 72];
    __shared__ float Ss[64 * 65];
    __shared__ float red[64 * 4];
    __shared__ float dinv[64];
    __shared__ float xbar[256];
    __shared__ float gacc[512];
    __shared__ float out6[6];

    const int t = threadIdx.x;
    const int lane = t & 63, wave = t >> 6;
    const int lr = lane & 15, q8 = lane >> 4;
    const int b = blockIdx.x;
    const f32x4 z4 = {0.f, 0.f, 0.f, 0.f};

    gacc[t] = 0.f;
    gacc[t + 256] = 0.f;
    if (t < 6) out6[t] = 0.f;

    {   // stage Xp[b] -> Xs (2048 x 16B chunks, 8 issues, XOR swizzle)
        const u16* xg = Xp + (size_t)b * 64 * 256;
#pragma unroll
        for (int it = 0; it < 8; ++it) {
            int c = it * 256 + wave * 64 + lane;
            int row = c >> 5, s = c & 31;
            int g = (s & 24) | ((s & 7) ^ (row & 7));
            async16(&Xs[(it * 256 + wave * 64) * 8], xg + (size_t)row * 256 + g * 8);
        }
    }
    __syncthreads();

    {   // xbar = column means of Xp[b]
        int col = t;
        int g = col >> 3, e = col & 7;
        float s = 0.f;
        for (int row = 0; row < 64; ++row) {
            int sw = (g & 24) | ((g & 7) ^ (row & 7));
            s += bf2f(Xs[row * 256 + sw * 8 + e]);
        }
        xbar[col] = s * (1.0f / 64.0f);
    }

    for (int h = 0; h < 8; ++h) {
        __syncthreads();
        // --- QKV GEMM: 12 col-tiles (q0..3,k4..7,v8..11); wave owns 3 tiles
        f32x4 acc[3][4];
#pragma unroll
        for (int jt = 0; jt < 3; ++jt)
#pragma unroll
            for (int i = 0; i < 4; ++i) acc[jt][i] = z4;
#pragma unroll
        for (int kk = 0; kk < 8; ++kk) {
            bf16x8 af[4];
#pragma unroll
            for (int i = 0; i < 4; ++i) {
                int m = i * 16 + lr;
                int g = kk * 4 + q8;
                int s = (g & 24) | ((g & 7) ^ (m & 7));
                af[i] = *(const bf16x8*)&Xs[m * 256 + s * 8];
            }
#pragma unroll
            for (int jt = 0; jt < 3; ++jt) {
                int jj = wave * 3 + jt;
                int sec = jj >> 2;
                int r = sec * 512 + h * 64 + (jj & 3) * 16 + lr;
                bf16x8 bfv = *(const bf16x8*)(WT + (size_t)r * 256 + kk * 32 + q8 * 8);
#pragma unroll
                for (int i = 0; i < 4; ++i)
                    acc[jt][i] = __builtin_amdgcn_mfma_f32_16x16x32_bf16(
                        af[i], bfv, acc[jt][i], 0, 0, 0);
            }
        }
#pragma unroll
        for (int jt = 0; jt < 3; ++jt) {
            int jj = wave * 3 + jt;
            int sec = jj >> 2;
            int colh = (jj & 3) * 16 + lr;
            const float* bptr = (sec == 0) ? bq : (sec == 1) ? bk : bv;
            float bias = bptr[h * 64 + colh];
#pragma unroll
            for (int i = 0; i < 4; ++i)
#pragma unroll
                for (int r2 = 0; r2 < 4; ++r2) {
                    int row = i * 16 + q8 * 4 + r2;
                    float v = acc[jt][i][r2] + bias;
                    if (sec == 0)      Qs[row * 72 + colh] = f2bf(v * 0.125f);
                    else if (sec == 1) Ks[row * 72 + colh] = f2bf(v);
                    else               Vt[colh * 72 + row] = f2bf(v);
                }
        }
        __syncthreads();
        // --- S = (q/8) @ k^T + mask ; wave owns rows wave*16..+15
        {
            f32x4 sacc[4];
#pragma unroll
            for (int j = 0; j < 4; ++j) sacc[j] = z4;
            int m = wave * 16 + lr;
#pragma unroll
            for (int k2 = 0; k2 < 2; ++k2) {
                bf16x8 aq = *(const bf16x8*)&Qs[m * 72 + k2 * 32 + q8 * 8];
#pragma unroll
                for (int j = 0; j < 4; ++j) {
                    int n = j * 16 + lr;
                    bf16x8 bk8 = *(const bf16x8*)&Ks[n * 72 + k2 * 32 + q8 * 8];
                    sacc[j] = __builtin_amdgcn_mfma_f32_16x16x32_bf16(
                        aq, bk8, sacc[j], 0, 0, 0);
                }
            }
#pragma unroll
            for (int j = 0; j < 4; ++j)
#pragma unroll
                for (int r2 = 0; r2 < 4; ++r2) {
                    int row = wave * 16 + q8 * 4 + r2;
                    int cn = j * 16 + lr;
                    Ss[row * 65 + cn] = sacc[j][r2] + Mmask[row * 64 + cn];
                }
        }
        __syncthreads();
        // --- softmax over src (cols); 4 threads per row
        {
            int row = t >> 2, part = t & 3;
            const float* srow = &Ss[row * 65 + part * 16];
            float mx = -1e38f;
            for (int c = 0; c < 16; ++c) mx = fmaxf(mx, srow[c]);
            red[row * 4 + part] = mx;
            __syncthreads();
            float m = fmaxf(fmaxf(red[row * 4], red[row * 4 + 1]),
                            fmaxf(red[row * 4 + 2], red[row * 4 + 3]));
            bool dead = (m < -1e29f);
            float sum = 0.f;
            u16* prow = &Ps[row * 72 + part * 16];
            for (int c = 0; c < 16; ++c) {
                float p = dead ? 0.f : __expf(srow[c] - m);
                sum += p;
                prow[c] = f2bf(p);
            }
            __syncthreads();
            red[row * 4 + part] = sum;
            __syncthreads();
            if (part == 0)
                dinv[row] = 1.0f / (red[row * 4] + red[row * 4 + 1] +
                                    red[row * 4 + 2] + red[row * 4 + 3] + 1e-16f);
        }
        __syncthreads();
        // --- PV: num = P @ v ; accumulate graph mean
        {
            f32x4 pacc[4];
#pragma unroll
            for (int j = 0; j < 4; ++j) pacc[j] = z4;
            int m = wave * 16 + lr;
#pragma unroll
            for (int k2 = 0; k2 < 2; ++k2) {
                bf16x8 ap = *(const bf16x8*)&Ps[m * 72 + k2 * 32 + q8 * 8];
#pragma unroll
                for (int j = 0; j < 4; ++j) {
                    int n = j * 16 + lr;
                    bf16x8 bv8 = *(const bf16x8*)&Vt[n * 72 + k2 * 32 + q8 * 8];
                    pacc[j] = __builtin_amdgcn_mfma_f32_16x16x32_bf16(
                        ap, bv8, pacc[j], 0, 0, 0);
                }
            }
#pragma unroll
            for (int j = 0; j < 4; ++j) {
                float partial = 0.f;
#pragma unroll
                for (int r2 = 0; r2 < 4; ++r2) {
                    int row = wave * 16 + q8 * 4 + r2;
                    partial += pacc[j][r2] * dinv[row];
                }
                atomicAdd(&gacc[h * 64 + j * 16 + lr], partial * (1.0f / 64.0f));
            }
        }
    }
    __syncthreads();
    // --- skip: gacc[c] += xbar @ Ws^T[c] + bs[c]
    {
#pragma unroll
        for (int half = 0; half < 2; ++half) {
            int cp = t + half * 256;
            const u16* wrow = WT + (size_t)(1536 + cp) * 256;
            float s = bs[cp];
            for (int k = 0; k < 256; k += 8) {
                uint4 u = *(const uint4*)(wrow + k);
                const u16* us = (const u16*)&u;
#pragma unroll
                for (int e = 0; e < 8; ++e) s += bf2f(us[e]) * xbar[k + e];
            }
            gacc[cp] += s;
        }
    }
    __syncthreads();
    // --- out = gacc @ Wr + br
    {
        float pj[6] = {0.f, 0.f, 0.f, 0.f, 0.f, 0.f};
#pragma unroll
        for (int half = 0; half < 2; ++half) {
            int cp = t + half * 256;
            float g = gacc[cp];
#pragma unroll
            for (int j = 0; j < 6; ++j) pj[j] += g * Wr[cp * 6 + j];
        }
#pragma unroll
        for (int j = 0; j < 6; ++j) {
            float v = pj[j];
            for (int off = 32; off; off >>= 1) v += __shfl_down(v, off);
            if (lane == 0) atomicAdd(&out6[j], v);
        }
    }
    __syncthreads();
    if (t < 6) out[b * 6 + t] = out6[t] + br[t];
}

// ---------------------------------------------------------------------------
extern "C" void kernel_launch(void* const* d_in, const int* in_sizes, int n_in,
                              void* d_out, int out_size, void* d_ws, size_t ws_size,
                              hipStream_t stream)
{
    (void)in_sizes; (void)n_in; (void)out_size; (void)ws_size;
    const float* X  = (const float*)d_in[0];
    const int*   ei = (const int*)d_in[1];
    const float* Wp = (const float*)d_in[2];
    const float* bp = (const float*)d_in[3];
    const float* Wq = (const float*)d_in[4];
    const float* bq = (const float*)d_in[5];
    const float* Wk = (const float*)d_in[6];
    const float* bk = (const float*)d_in[7];
    const float* Wv = (const float*)d_in[8];
    const float* bv = (const float*)d_in[9];
    const float* Wsk = (const float*)d_in[10];
    const float* bs = (const float*)d_in[11];
    const float* Wr = (const float*)d_in[12];
    const float* br = (const float*)d_in[13];
    float* out = (float*)d_out;

    char* ws = (char*)d_ws;
    u16*   WpT = (u16*)(ws);                                  // 1 MiB
    u16*   WT  = (u16*)(ws + (1u << 20));                     // 1 MiB
    float* Mm  = (float*)(ws + (2u << 20));                   // 16 KiB
    u16*   Xp  = (u16*)(ws + (2u << 20) + (1u << 16));        // 32 MiB

    hipLaunchKernelGGL(prep_weights, dim3(4096), dim3(256), 0, stream,
                       Wp, Wq, Wk, Wv, Wsk, WpT, WT);
    hipLaunchKernelGGL(prep_mask, dim3(1), dim3(256), 0, stream, ei, Mm);
    hipLaunchKernelGGL(gemm1, dim3(512, 2), dim3(256), 0, stream, X, WpT, bp, Xp);
    hipLaunchKernelGGL(fused_attn, dim3(1024), dim3(256), 0, stream,
                       Xp, WT, Mm, bq, bk, bv, bs, Wr, br, out);
}

// Round 2
// 1154.677 us; speedup vs baseline: 1.0672x; 1.0672x over previous
//
#include <hip/hip_runtime.h>

typedef unsigned short u16;
typedef short bf16x8 __attribute__((ext_vector_type(8)));
typedef float f32x4 __attribute__((ext_vector_type(4)));

__device__ __forceinline__ u16 f2bf(float f) {
    unsigned u = __float_as_uint(f);
    u = (u + 0x7fffu + ((u >> 16) & 1u)) >> 16;
    return (u16)u;
}
__device__ __forceinline__ float bf2f(u16 h) {
    return __uint_as_float(((unsigned)h) << 16);
}
// cheap round-to-nearest (ties-away) pack: 4-5 VALU vs ~10 for RTNE
__device__ __forceinline__ unsigned pk2c(float a, float b) {
    return ((__float_as_uint(a) + 0x8000u) >> 16) |
           ((__float_as_uint(b) + 0x8000u) & 0xffff0000u);
}
__device__ __forceinline__ void async16(void* lds, const void* g) {
    __builtin_amdgcn_global_load_lds(
        (const __attribute__((address_space(1))) void*)g,
        (__attribute__((address_space(3))) void*)lds, 16, 0, 0);
}

// ---------------------------------------------------------------------------
// prep_weights: WpT bf16 [256][2048] (=Wp^T); WT bf16 [1536][256]
// (rows: q 0..511 | k 512..1023 | v 1024..1535; col = D index). Writes coalesced.
// ---------------------------------------------------------------------------
__global__ __launch_bounds__(256) void prep_weights(
    const float* __restrict__ Wp, const float* __restrict__ Wq,
    const float* __restrict__ Wk, const float* __restrict__ Wv,
    u16* __restrict__ WpT, u16* __restrict__ WT)
{
    int id = blockIdx.x * 256 + threadIdx.x;   // 0 .. 917503
    if (id < 524288) {
        int n = id >> 11, k = id & 2047;
        WpT[(size_t)n * 2048 + k] = f2bf(Wp[(size_t)k * 256 + n]);
    } else {
        int id2 = id - 524288;
        int k = id2 & 255;
        int o = (id2 >> 8) & 511;
        int mat = id2 >> 17;                                 // 0..2
        const float* W = (mat == 0) ? Wq : (mat == 1) ? Wk : Wv;
        WT[(size_t)(mat * 512 + o) * 256 + k] = f2bf(W[(size_t)k * 512 + o]);
    }
}

// ---------------------------------------------------------------------------
// prep_small: blocks 0..7: Wsr[256][6] = Ws @ Wr (32 d-rows per block).
// block 8: mask M[dst][src] = ln(mult) / -1e30, and c0[6] = (bs+bv)@Wr + br.
// ---------------------------------------------------------------------------
__global__ __launch_bounds__(256) void prep_small(
    const int* __restrict__ ei, const float* __restrict__ Wsf,
    const float* __restrict__ Wr, const float* __restrict__ bsf,
    const float* __restrict__ bvf, const float* __restrict__ brf,
    float* __restrict__ Mm, float* __restrict__ Wsr, float* __restrict__ c0)
{
    int t = threadIdx.x, bx = blockIdx.x;
    if (bx < 8) {
        int d = bx * 32 + (t >> 3);
        int os = t & 7;
        float a[6] = {0.f, 0.f, 0.f, 0.f, 0.f, 0.f};
        for (int i = 0; i < 64; ++i) {
            int o = os * 64 + i;
            float w = Wsf[(size_t)d * 512 + o];
#pragma unroll
            for (int j = 0; j < 6; ++j) a[j] += w * Wr[o * 6 + j];
        }
#pragma unroll
        for (int j = 0; j < 6; ++j) {
            a[j] += __shfl_xor(a[j], 1);
            a[j] += __shfl_xor(a[j], 2);
            a[j] += __shfl_xor(a[j], 4);
        }
        if (os == 0) {
#pragma unroll
            for (int j = 0; j < 6; ++j) Wsr[d * 6 + j] = a[j];
        }
    } else {
        __shared__ int cnt[4096];
        __shared__ float c6[6];
        for (int i = t; i < 4096; i += 256) cnt[i] = 0;
        if (t < 6) c6[t] = 0.f;
        __syncthreads();
        for (int e = t; e < 1024; e += 256) {
            int s = ei[e];
            int d = ei[1024 + e];
            atomicAdd(&cnt[d * 64 + s], 1);
        }
        __syncthreads();
        for (int i = t; i < 4096; i += 256) {
            int c = cnt[i];
            Mm[i] = (c > 0) ? logf((float)c) : -1e30f;
        }
        // c0
        float a[6] = {0.f, 0.f, 0.f, 0.f, 0.f, 0.f};
        for (int o = t; o < 512; o += 256) {
            float bb = bsf[o] + bvf[o];
#pragma unroll
            for (int j = 0; j < 6; ++j) a[j] += bb * Wr[o * 6 + j];
        }
#pragma unroll
        for (int j = 0; j < 6; ++j) {
            float v = a[j];
            for (int off = 32; off; off >>= 1) v += __shfl_down(v, off);
            if ((t & 63) == 0) atomicAdd(&c6[j], v);
        }
        __syncthreads();
        if (t < 6) c0[t] = c6[t] + brf[t];
    }
}

// ---------------------------------------------------------------------------
// gemm1: Xp_bf16[65536][256] = bf16(X[65536][2048]) @ bf16(Wp) + bp
// ---------------------------------------------------------------------------
__global__ __launch_bounds__(256) void gemm1(const float* __restrict__ X,
                                             const u16* __restrict__ WpT,
                                             const float* __restrict__ bp,
                                             u16* __restrict__ Xp)
{
    __shared__ alignas(16) u16 As[128 * 40];
    __shared__ alignas(16) u16 Bs[128 * 32];
    const int t = threadIdx.x;
    const int lane = t & 63, wave = t >> 6;
    const int m0 = blockIdx.x * 128, n0 = blockIdx.y * 128;
    const int wm = (wave >> 1) * 64, wn = (wave & 1) * 64;
    const int lr = lane & 15, q8 = lane >> 4;

    const int ar = t >> 1, ah = (t & 1) * 16;
    const float* aptr = X + (size_t)(m0 + ar) * 2048 + ah;

    const int c0 = wave * 64 + lane;
    const int c1 = 256 + wave * 64 + lane;
    const int br0 = c0 >> 2, bg0 = (c0 & 3) ^ (br0 & 3);
    const int br1 = c1 >> 2, bg1 = (c1 & 3) ^ (br1 & 3);
    const u16* bbase = WpT + (size_t)n0 * 2048;
    u16* blds0 = &Bs[(wave * 64) * 8];
    u16* blds1 = &Bs[(256 + wave * 64) * 8];

    const f32x4 z4 = {0.f, 0.f, 0.f, 0.f};
    f32x4 acc[4][4];
#pragma unroll
    for (int i = 0; i < 4; ++i)
#pragma unroll
        for (int j = 0; j < 4; ++j) acc[i][j] = z4;

    for (int kk = 0; kk < 64; ++kk) {
        const int k0 = kk * 32;
        async16(blds0, bbase + (size_t)br0 * 2048 + k0 + bg0 * 8);
        async16(blds1, bbase + (size_t)br1 * 2048 + k0 + bg1 * 8);
        const float4 x0 = *(const float4*)(aptr + k0);
        const float4 x1 = *(const float4*)(aptr + k0 + 4);
        const float4 x2 = *(const float4*)(aptr + k0 + 8);
        const float4 x3 = *(const float4*)(aptr + k0 + 12);
        uint4 p0, p1;
        p0.x = pk2c(x0.x, x0.y); p0.y = pk2c(x0.z, x0.w);
        p0.z = pk2c(x1.x, x1.y); p0.w = pk2c(x1.z, x1.w);
        p1.x = pk2c(x2.x, x2.y); p1.y = pk2c(x2.z, x2.w);
        p1.z = pk2c(x3.x, x3.y); p1.w = pk2c(x3.z, x3.w);
        *(uint4*)&As[ar * 40 + ah] = p0;
        *(uint4*)&As[ar * 40 + ah + 8] = p1;
        __syncthreads();
        bf16x8 af[4], bfr[4];
#pragma unroll
        for (int i = 0; i < 4; ++i)
            af[i] = *(const bf16x8*)&As[(wm + i * 16 + lr) * 40 + q8 * 8];
#pragma unroll
        for (int j = 0; j < 4; ++j) {
            int rn = wn + j * 16 + lr;
            bfr[j] = *(const bf16x8*)&Bs[rn * 32 + ((q8 ^ (rn & 3)) * 8)];
        }
#pragma unroll
        for (int i = 0; i < 4; ++i)
#pragma unroll
            for (int j = 0; j < 4; ++j)
                acc[i][j] = __builtin_amdgcn_mfma_f32_16x16x32_bf16(
                    af[i], bfr[j], acc[i][j], 0, 0, 0);
        __syncthreads();
    }
#pragma unroll
    for (int j = 0; j < 4; ++j) {
        const int col = n0 + wn + j * 16 + lr;
        const float bias = bp[col];
#pragma unroll
        for (int i = 0; i < 4; ++i)
#pragma unroll
            for (int r = 0; r < 4; ++r) {
                int row = m0 + wm + i * 16 + q8 * 4 + r;
                Xp[(size_t)row * 256 + col] = f2bf(acc[i][j][r] + bias);
            }
    }
}

// ---------------------------------------------------------------------------
// skip_out: out[b][:] = xbar[b] @ Wsr + c0   (pre-writes output; attn adds)
// ---------------------------------------------------------------------------
__global__ __launch_bounds__(256) void skip_out(const u16* __restrict__ Xp,
                                                const float* __restrict__ Wsr,
                                                const float* __restrict__ c0,
                                                float* __restrict__ out)
{
    __shared__ float acc6[6];
    int t = threadIdx.x, b = blockIdx.x;
    if (t < 6) acc6[t] = 0.f;
    __syncthreads();
    const u16* xg = Xp + (size_t)b * 16384;
    float s = 0.f;
#pragma unroll 8
    for (int n = 0; n < 64; ++n) s += bf2f(xg[n * 256 + t]);
    float xv = s * (1.0f / 64.0f);
#pragma unroll
    for (int j = 0; j < 6; ++j) {
        float v = xv * Wsr[t * 6 + j];
        for (int off = 32; off; off >>= 1) v += __shfl_down(v, off);
        if ((t & 63) == 0) atomicAdd(&acc6[j], v);
    }
    __syncthreads();
    if (t < 6) out[b * 6 + t] = acc6[t] + c0[t];
}

// ---------------------------------------------------------------------------
// attn: one block per (b,h). Stage Xp[b] -> LDS; QKV via MFMA (B from L2);
// S = qk^T/8 + mask (MFMA); in-register softmax; colsum(Pn)/64 -> w;
// y = w @ V; out[b] += y @ Wr_h  (6 atomics).
// ---------------------------------------------------------------------------
__global__ __launch_bounds__(256, 2) void attn(
    const u16* __restrict__ Xp, const u16* __restrict__ WT,
    const float* __restrict__ Mm, const float* __restrict__ bq,
    const float* __restrict__ bk, const float* __restrict__ Wr,
    float* __restrict__ out)
{
    __shared__ alignas(16) u16 Xs[64 * 256];
    __shared__ alignas(16) u16 Qs[64 * 72];
    __shared__ alignas(16) u16 Ks[64 * 72];
    __shared__ alignas(16) u16 Vs[64 * 72];
    __shared__ float w_l[64];
    __shared__ float y_l[64];

    const int t = threadIdx.x;
    const int lane = t & 63, wave = t >> 6;
    const int lr = lane & 15, q8 = lane >> 4;
    const int bh = blockIdx.x, b = bh >> 3, h = bh & 7;
    const f32x4 z4 = {0.f, 0.f, 0.f, 0.f};

    if (t < 64) { w_l[t] = 0.f; y_l[t] = 0.f; }

    {   // stage Xp[b] -> Xs, XOR-swizzled 16B chunks
        const u16* xg = Xp + (size_t)b * 16384;
#pragma unroll
        for (int it = 0; it < 8; ++it) {
            int c = it * 256 + t;
            int row = c >> 5, s = c & 31;
            int g = (s & 24) | ((s & 7) ^ (row & 7));
            async16(&Xs[(it * 256 + wave * 64) * 8], xg + (size_t)row * 256 + g * 8);
        }
    }
    __syncthreads();

    // --- QKV GEMM: 12 col-tiles of 16 (q0-3,k4-7,v8-11); wave owns 3
    f32x4 acc[3][4];
#pragma unroll
    for (int jt = 0; jt < 3; ++jt)
#pragma unroll
        for (int i = 0; i < 4; ++i) acc[jt][i] = z4;
    const int jj0 = wave * 3;
#pragma unroll 2
    for (int kk = 0; kk < 8; ++kk) {
        bf16x8 af[4];
#pragma unroll
        for (int i = 0; i < 4; ++i) {
            int m = i * 16 + lr;
            int g = kk * 4 + q8;
            int s = (g & 24) | ((g & 7) ^ (m & 7));
            af[i] = *(const bf16x8*)&Xs[m * 256 + s * 8];
        }
#pragma unroll
        for (int jt = 0; jt < 3; ++jt) {
            int jj = jj0 + jt, sec = jj >> 2;
            int r = sec * 512 + h * 64 + (jj & 3) * 16 + lr;
            bf16x8 bfv = *(const bf16x8*)(WT + (size_t)r * 256 + kk * 32 + q8 * 8);
#pragma unroll
            for (int i = 0; i < 4; ++i)
                acc[jt][i] = __builtin_amdgcn_mfma_f32_16x16x32_bf16(
                    af[i], bfv, acc[jt][i], 0, 0, 0);
        }
    }
    // epilogue -> LDS (pad 72); q scaled 1/8 w/ bias, k w/ bias, v raw
#pragma unroll
    for (int jt = 0; jt < 3; ++jt) {
        int jj = jj0 + jt, sec = jj >> 2;
        int colh = (jj & 3) * 16 + lr;
        float bias = (sec == 0) ? bq[h * 64 + colh]
                   : (sec == 1) ? bk[h * 64 + colh] : 0.f;
#pragma unroll
        for (int i = 0; i < 4; ++i)
#pragma unroll
            for (int r2 = 0; r2 < 4; ++r2) {
                int row = i * 16 + q8 * 4 + r2;
                float v = acc[jt][i][r2] + bias;
                if (sec == 0)      Qs[row * 72 + colh] = f2bf(v * 0.125f);
                else if (sec == 1) Ks[row * 72 + colh] = f2bf(v);
                else               Vs[row * 72 + colh] = f2bf(v);
            }
    }
    __syncthreads();

    // --- S-MFMA: wave owns dst rows wave*16..+15
    f32x4 sacc[4];
#pragma unroll
    for (int j = 0; j < 4; ++j) sacc[j] = z4;
#pragma unroll
    for (int k2 = 0; k2 < 2; ++k2) {
        bf16x8 aq = *(const bf16x8*)&Qs[(wave * 16 + lr) * 72 + k2 * 32 + q8 * 8];
#pragma unroll
        for (int j = 0; j < 4; ++j) {
            bf16x8 bk8 = *(const bf16x8*)&Ks[(j * 16 + lr) * 72 + k2 * 32 + q8 * 8];
            sacc[j] = __builtin_amdgcn_mfma_f32_16x16x32_bf16(aq, bk8, sacc[j], 0, 0, 0);
        }
    }
    // --- mask + in-register softmax (rows in C layout)
    const int dst0 = wave * 16 + q8 * 4;
    float p[4][4];
#pragma unroll
    for (int r2 = 0; r2 < 4; ++r2) {
        float m = -1e38f;
#pragma unroll
        for (int j = 0; j < 4; ++j) {
            sacc[j][r2] += Mm[(dst0 + r2) * 64 + j * 16 + lr];
            m = fmaxf(m, sacc[j][r2]);
        }
        m = fmaxf(m, __shfl_xor(m, 1));
        m = fmaxf(m, __shfl_xor(m, 2));
        m = fmaxf(m, __shfl_xor(m, 4));
        m = fmaxf(m, __shfl_xor(m, 8));
        bool dead = (m < -1e29f);
        float rs = 0.f;
#pragma unroll
        for (int j = 0; j < 4; ++j) {
            float pv = dead ? 0.f : __expf(sacc[j][r2] - m);
            p[j][r2] = pv;
            rs += pv;
        }
        rs += __shfl_xor(rs, 1);
        rs += __shfl_xor(rs, 2);
        rs += __shfl_xor(rs, 4);
        rs += __shfl_xor(rs, 8);
        float sc = 1.0f / (rs + 1e-16f) * (1.0f / 64.0f);
#pragma unroll
        for (int j = 0; j < 4; ++j) p[j][r2] *= sc;
    }
    // --- column sums -> w_l
#pragma unroll
    for (int j = 0; j < 4; ++j) {
        float cw = p[j][0] + p[j][1] + p[j][2] + p[j][3];
        cw += __shfl_xor(cw, 16);
        cw += __shfl_xor(cw, 32);
        if (lane < 16) atomicAdd(&w_l[j * 16 + lr], cw);
    }
    __syncthreads();
    // --- y[c] = sum_src w[src] * V[src][c]
    {
        int c = t & 63, sg = t >> 6;
        float part = 0.f;
#pragma unroll
        for (int i = 0; i < 16; ++i) {
            int src = sg * 16 + i;
            part += w_l[src] * bf2f(Vs[src * 72 + c]);
        }
        atomicAdd(&y_l[c], part);
    }
    __syncthreads();
    // --- out[b] += y @ Wr_h
    if (t < 64) {
        float yv = y_l[t];
#pragma unroll
        for (int j = 0; j < 6; ++j) {
            float v = yv * Wr[(h * 64 + t) * 6 + j];
            for (int off = 32; off; off >>= 1) v += __shfl_down(v, off);
            if (t == 0) atomicAdd(&out[b * 6 + j], v);
        }
    }
}

// ---------------------------------------------------------------------------
extern "C" void kernel_launch(void* const* d_in, const int* in_sizes, int n_in,
                              void* d_out, int out_size, void* d_ws, size_t ws_size,
                              hipStream_t stream)
{
    (void)in_sizes; (void)n_in; (void)out_size; (void)ws_size;
    const float* X  = (const float*)d_in[0];
    const int*   ei = (const int*)d_in[1];
    const float* Wp = (const float*)d_in[2];
    const float* bp = (const float*)d_in[3];
    const float* Wq = (const float*)d_in[4];
    const float* bq = (const float*)d_in[5];
    const float* Wk = (const float*)d_in[6];
    const float* bk = (const float*)d_in[7];
    const float* Wv = (const float*)d_in[8];
    const float* bv = (const float*)d_in[9];
    const float* Wsk = (const float*)d_in[10];
    const float* bs = (const float*)d_in[11];
    const float* Wr = (const float*)d_in[12];
    const float* br = (const float*)d_in[13];
    float* out = (float*)d_out;

    char* ws = (char*)d_ws;
    u16*   WpT = (u16*)(ws);                                  // 1 MiB
    u16*   WT  = (u16*)(ws + (1u << 20));                     // 768 KiB
    float* Mm  = (float*)(ws + 0x1C0000u);                    // 16 KiB
    float* Wsr = (float*)(ws + 0x1C4000u);                    // 6 KiB
    float* c0  = (float*)(ws + 0x1C8000u);                    // 24 B
    u16*   Xp  = (u16*)(ws + (2u << 20));                     // 32 MiB

    hipLaunchKernelGGL(prep_weights, dim3(3584), dim3(256), 0, stream,
                       Wp, Wq, Wk, Wv, WpT, WT);
    hipLaunchKernelGGL(prep_small, dim3(9), dim3(256), 0, stream,
                       ei, Wsk, Wr, bs, bv, br, Mm, Wsr, c0);
    hipLaunchKernelGGL(gemm1, dim3(512, 2), dim3(256), 0, stream, X, WpT, bp, Xp);
    hipLaunchKernelGGL(skip_out, dim3(1024), dim3(256), 0, stream, Xp, Wsr, c0, out);
    hipLaunchKernelGGL(attn, dim3(8192), dim3(256), 0, stream,
                       Xp, WT, Mm, bq, bk, Wr, out);
}